// Round 1
// baseline (1008.685 us; speedup 1.0000x reference)
//
#include <hip/hip_runtime.h>
#include <math.h>

#define D 128
#define NNODES 8192
#define NEDGES 16384
#define NSTEMS 4096
#define NGRAPHS 256
#define NSTEPS 12
#define OPS 105
#define SLOPE 0.01f
#define SLOC_CAP 1024

__device__ __forceinline__ float leaky(float x) { return x > 0.f ? x : SLOPE * x; }
__device__ __forceinline__ float sigmoidf(float x) { return 1.f / (1.f + expf(-x)); }

// ---------------- setup kernels ----------------

__global__ void k_zero(float* p, int n) {
    int i = blockIdx.x * 256 + threadIdx.x;
    if (i < n) p[i] = 0.f;
}

__global__ void k_deg(const int* __restrict__ eidx, int* __restrict__ deg) {
    int e = blockIdx.x * 256 + threadIdx.x;
    if (e < NEDGES) atomicAdd(&deg[eidx[NEDGES + e]], 1);
}

// 256 threads, each owns 32 consecutive nodes; block-level scan.
__global__ void k_scan(const int* __restrict__ deg, int* __restrict__ row_start,
                       float* __restrict__ inv_deg) {
    __shared__ int sums[256];
    int t = threadIdx.x;
    int base = t * 32;
    int s = 0;
    for (int k = 0; k < 32; ++k) s += deg[base + k];
    sums[t] = s;
    __syncthreads();
    for (int off = 1; off < 256; off <<= 1) {
        int v = sums[t];
        int u = (t >= off) ? sums[t - off] : 0;
        __syncthreads();
        sums[t] = v + u;
        __syncthreads();
    }
    int run = sums[t] - s;   // exclusive prefix of this thread's chunk
    for (int k = 0; k < 32; ++k) {
        int d = deg[base + k];
        row_start[base + k] = run;
        run += d;
        inv_deg[base + k] = (d > 0) ? (1.0f / (float)d) : 0.0f;
    }
    if (t == 255) row_start[NNODES] = run;
}

__global__ void k_scatter(const int* __restrict__ eidx, const int* __restrict__ row_start,
                          int* __restrict__ fill, int* __restrict__ edge_list) {
    int e = blockIdx.x * 256 + threadIdx.x;
    if (e < NEDGES) {
        int d = eidx[NEDGES + e];
        int pos = row_start[d] + atomicAdd(&fill[d], 1);
        edge_list[pos] = e;
    }
}

__device__ __forceinline__ void tr(const float* __restrict__ src, float* __restrict__ dst,
                                   int rows, int cols, int idx) {
    if (idx < rows * cols) {
        int r = idx / cols;
        int c = idx - r * cols;
        dst[c * rows + r] = src[idx];
    }
}

__global__ void k_transpose_all(
    const float* gih, const float* ghh, const float* bw1, const float* bw2,
    const float* sw1, const float* sw2, const float* sw3, const float* gw1,
    float* WihT, float* WhhT, float* w1T, float* w2T,
    float* s1T, float* s2T, float* s3T, float* g1T) {
    int idx = blockIdx.x * 256 + threadIdx.x;
    switch (blockIdx.y) {
        case 0: tr(gih, WihT, 384, 128, idx); break;
        case 1: tr(ghh, WhhT, 384, 128, idx); break;
        case 2: tr(bw1, w1T, 128, 128, idx); break;
        case 3: tr(bw2, w2T, 128, 128, idx); break;
        case 4: tr(sw1, s1T, 128, 256, idx); break;
        case 5: tr(sw2, s2T, 128, 128, idx); break;
        case 6: tr(sw3, s3T, 105, 128, idx); break;
        case 7: tr(gw1, g1T, 128, 128, idx); break;
    }
}

// ---------------- node init: out = act(emb@W1.T+b1)@W2.T+b2 ----------------
// 256 threads, 16 nodes/block; sub = tid>>7 handles 8 nodes, j = tid&127 is the column.
__global__ __launch_bounds__(256) void k_init(
    const int* __restrict__ x, const float* __restrict__ embBlock,
    const float* __restrict__ w1T, const float* __restrict__ b1,
    const float* __restrict__ w2T, const float* __restrict__ b2,
    float* __restrict__ outA, float* __restrict__ hF) {
    __shared__ float es[16][D];
    __shared__ float ts[16][D];
    int tid = threadIdx.x;
    int j = tid & 127;
    int sub = tid >> 7;
    int n0 = blockIdx.x * 16;

    for (int ss = 0; ss < 8; ++ss) {
        int nn = sub * 8 + ss;
        es[nn][j] = embBlock[x[n0 + nn] * D + j];
    }
    __syncthreads();

    float acc[8];
    float bb = b1[j];
#pragma unroll
    for (int ss = 0; ss < 8; ++ss) acc[ss] = bb;
    for (int i = 0; i < D; i += 4) {
        float w0 = w1T[(i + 0) * D + j];
        float w1 = w1T[(i + 1) * D + j];
        float w2 = w1T[(i + 2) * D + j];
        float w3 = w1T[(i + 3) * D + j];
#pragma unroll
        for (int ss = 0; ss < 8; ++ss) {
            float4 v = *(const float4*)&es[sub * 8 + ss][i];
            acc[ss] += v.x * w0 + v.y * w1 + v.z * w2 + v.w * w3;
        }
    }
#pragma unroll
    for (int ss = 0; ss < 8; ++ss) ts[sub * 8 + ss][j] = leaky(acc[ss]);
    __syncthreads();

    bb = b2[j];
#pragma unroll
    for (int ss = 0; ss < 8; ++ss) acc[ss] = bb;
    for (int i = 0; i < D; i += 4) {
        float w0 = w2T[(i + 0) * D + j];
        float w1 = w2T[(i + 1) * D + j];
        float w2v = w2T[(i + 2) * D + j];
        float w3 = w2T[(i + 3) * D + j];
#pragma unroll
        for (int ss = 0; ss < 8; ++ss) {
            float4 v = *(const float4*)&ts[sub * 8 + ss][i];
            acc[ss] += v.x * w0 + v.y * w1 + v.z * w2v + v.w * w3;
        }
    }
#pragma unroll
    for (int ss = 0; ss < 8; ++ss) {
        int n = n0 + sub * 8 + ss;
        outA[n * D + j] = acc[ss];
        hF[n * D + j] = acc[ss];
    }
}

// ---------------- one conv+GRU step, fully fused per 16-node block ----------------
__global__ __launch_bounds__(256) void k_nodestep(
    const float* __restrict__ outCur, float* __restrict__ outNxt, float* __restrict__ hF,
    const float* __restrict__ bond, const float* __restrict__ root, const float* __restrict__ cbias,
    const float* __restrict__ WihT, const float* __restrict__ WhhT,
    const float* __restrict__ bih, const float* __restrict__ bhh,
    const int* __restrict__ eidx, const int* __restrict__ eattr,
    const int* __restrict__ row_start, const int* __restrict__ edge_list,
    const float* __restrict__ inv_deg) {
    __shared__ float own[16][D];
    __shared__ float hs[16][D];
    __shared__ float ms[16][D];
    __shared__ float sloc[SLOC_CAP];
    const int tid = threadIdx.x;
    const int j = tid & 127;
    const int sub = tid >> 7;
    const int n0 = blockIdx.x * 16;

    for (int ss = 0; ss < 8; ++ss) {
        int nn = sub * 8 + ss;
        own[nn][j] = outCur[(n0 + nn) * D + j];
        hs[nn][j] = hF[(n0 + nn) * D + j];
    }
    const int p0 = row_start[n0];
    const int p1 = row_start[n0 + 16];

    // edge-dot phase: s_e = dot(out[src], bond[ea0]); 4 waves split the block's CSR range
    {
        int wave = tid >> 6;
        int lane = tid & 63;
        for (int p = p0 + wave; p < p1; p += 4) {
            int e = edge_list[p];
            int s = eidx[e];
            int a0 = eattr[2 * e];
            float v = outCur[s * D + lane] * bond[a0 * D + lane] +
                      outCur[s * D + 64 + lane] * bond[a0 * D + 64 + lane];
#pragma unroll
            for (int off = 32; off >= 1; off >>= 1) v += __shfl_xor(v, off, 64);
            int rel = p - p0;
            if (lane == 0 && rel < SLOC_CAP) sloc[rel] = v;
        }
    }
    __syncthreads();

    // conv: c = out@root + bias
    float acc[8];
    {
        float cb = cbias[j];
#pragma unroll
        for (int ss = 0; ss < 8; ++ss) acc[ss] = cb;
        for (int i = 0; i < D; i += 4) {
            float w0 = root[(i + 0) * D + j];
            float w1 = root[(i + 1) * D + j];
            float w2 = root[(i + 2) * D + j];
            float w3 = root[(i + 3) * D + j];
#pragma unroll
            for (int ss = 0; ss < 8; ++ss) {
                float4 v = *(const float4*)&own[sub * 8 + ss][i];
                acc[ss] += v.x * w0 + v.y * w1 + v.z * w2 + v.w * w3;
            }
        }
    }
    // aggregate rank-1 messages + activation -> m
    for (int ss = 0; ss < 8; ++ss) {
        int nn = sub * 8 + ss;
        int node = n0 + nn;
        float a = 0.f;
        int q0 = row_start[node], q1 = row_start[node + 1];
        for (int p = q0; p < q1; ++p) {
            int e = edge_list[p];
            int a1 = eattr[2 * e + 1];
            int rel = p - p0;
            float sv;
            if (rel < SLOC_CAP) sv = sloc[rel];
            else {  // safety fallback (never expected for this input)
                int s = eidx[e];
                int a0 = eattr[2 * e];
                sv = 0.f;
                for (int i = 0; i < D; ++i) sv += outCur[s * D + i] * bond[a0 * D + i];
            }
            a += sv * bond[a1 * D + j];
        }
        ms[nn][j] = leaky(acc[ss] + a * inv_deg[node]);
    }
    __syncthreads();

    // GRU input gates gi = m @ W_ih.T + b_ih
    float g0[8], g1[8], g2[8];
    {
        float b0 = bih[j], b1v = bih[D + j], b2v = bih[2 * D + j];
#pragma unroll
        for (int ss = 0; ss < 8; ++ss) { g0[ss] = b0; g1[ss] = b1v; g2[ss] = b2v; }
        for (int i = 0; i < D; i += 4) {
            float wa0 = WihT[(i + 0) * 384 + j], wa1 = WihT[(i + 1) * 384 + j],
                  wa2 = WihT[(i + 2) * 384 + j], wa3 = WihT[(i + 3) * 384 + j];
            float wb0 = WihT[(i + 0) * 384 + D + j], wb1 = WihT[(i + 1) * 384 + D + j],
                  wb2 = WihT[(i + 2) * 384 + D + j], wb3 = WihT[(i + 3) * 384 + D + j];
            float wc0 = WihT[(i + 0) * 384 + 2 * D + j], wc1 = WihT[(i + 1) * 384 + 2 * D + j],
                  wc2 = WihT[(i + 2) * 384 + 2 * D + j], wc3 = WihT[(i + 3) * 384 + 2 * D + j];
#pragma unroll
            for (int ss = 0; ss < 8; ++ss) {
                float4 v = *(const float4*)&ms[sub * 8 + ss][i];
                g0[ss] += v.x * wa0 + v.y * wa1 + v.z * wa2 + v.w * wa3;
                g1[ss] += v.x * wb0 + v.y * wb1 + v.z * wb2 + v.w * wb3;
                g2[ss] += v.x * wc0 + v.y * wc1 + v.z * wc2 + v.w * wc3;
            }
        }
    }
    // GRU hidden gates gh = h @ W_hh.T + b_hh, then combine
    {
        float q0a[8], q1a[8], q2a[8];
        float b0 = bhh[j], b1v = bhh[D + j], b2v = bhh[2 * D + j];
#pragma unroll
        for (int ss = 0; ss < 8; ++ss) { q0a[ss] = b0; q1a[ss] = b1v; q2a[ss] = b2v; }
        for (int i = 0; i < D; i += 4) {
            float wa0 = WhhT[(i + 0) * 384 + j], wa1 = WhhT[(i + 1) * 384 + j],
                  wa2 = WhhT[(i + 2) * 384 + j], wa3 = WhhT[(i + 3) * 384 + j];
            float wb0 = WhhT[(i + 0) * 384 + D + j], wb1 = WhhT[(i + 1) * 384 + D + j],
                  wb2 = WhhT[(i + 2) * 384 + D + j], wb3 = WhhT[(i + 3) * 384 + D + j];
            float wc0 = WhhT[(i + 0) * 384 + 2 * D + j], wc1 = WhhT[(i + 1) * 384 + 2 * D + j],
                  wc2 = WhhT[(i + 2) * 384 + 2 * D + j], wc3 = WhhT[(i + 3) * 384 + 2 * D + j];
#pragma unroll
            for (int ss = 0; ss < 8; ++ss) {
                float4 v = *(const float4*)&hs[sub * 8 + ss][i];
                q0a[ss] += v.x * wa0 + v.y * wa1 + v.z * wa2 + v.w * wa3;
                q1a[ss] += v.x * wb0 + v.y * wb1 + v.z * wb2 + v.w * wb3;
                q2a[ss] += v.x * wc0 + v.y * wc1 + v.z * wc2 + v.w * wc3;
            }
        }
#pragma unroll
        for (int ss = 0; ss < 8; ++ss) {
            int nn = sub * 8 + ss;
            float r = sigmoidf(g0[ss] + q0a[ss]);
            float z = sigmoidf(g1[ss] + q1a[ss]);
            float n = tanhf(g2[ss] + r * q2a[ss]);
            float hv = hs[nn][j];
            float hnew = (1.f - z) * n + z * hv;
            hF[(n0 + nn) * D + j] = hnew;
            outNxt[(n0 + nn) * D + j] = hnew;
        }
    }
}

// ---------------- stem head ----------------
__global__ __launch_bounds__(256) void k_stem(
    const float* __restrict__ out0, const int* __restrict__ sni, const int* __restrict__ stypes,
    const float* __restrict__ embStem,
    const float* __restrict__ w1T, const float* __restrict__ b1,
    const float* __restrict__ w2T, const float* __restrict__ b2,
    const float* __restrict__ w3T, const float* __restrict__ b3,
    float* __restrict__ dout) {
    __shared__ float cat[16][2 * D];
    __shared__ float s1[16][D];
    __shared__ float s2[16][D];
    int tid = threadIdx.x;
    int j = tid & 127;
    int sub = tid >> 7;
    int s0 = blockIdx.x * 16;

    for (int ss = 0; ss < 16; ++ss) {
        int s = s0 + ss;
        if (tid < 128) cat[ss][tid] = out0[sni[s] * D + tid];
        else cat[ss][tid] = embStem[stypes[s] * D + (tid - 128)];
    }
    __syncthreads();

    float acc[8];
    {
        float bb = b1[j];
#pragma unroll
        for (int ss = 0; ss < 8; ++ss) acc[ss] = bb;
        for (int i = 0; i < 2 * D; i += 4) {
            float w0 = w1T[(i + 0) * D + j];
            float w1 = w1T[(i + 1) * D + j];
            float w2 = w1T[(i + 2) * D + j];
            float w3 = w1T[(i + 3) * D + j];
#pragma unroll
            for (int ss = 0; ss < 8; ++ss) {
                float4 v = *(const float4*)&cat[sub * 8 + ss][i];
                acc[ss] += v.x * w0 + v.y * w1 + v.z * w2 + v.w * w3;
            }
        }
#pragma unroll
        for (int ss = 0; ss < 8; ++ss) s1[sub * 8 + ss][j] = leaky(acc[ss]);
    }
    __syncthreads();
    {
        float bb = b2[j];
#pragma unroll
        for (int ss = 0; ss < 8; ++ss) acc[ss] = bb;
        for (int i = 0; i < D; i += 4) {
            float w0 = w2T[(i + 0) * D + j];
            float w1 = w2T[(i + 1) * D + j];
            float w2 = w2T[(i + 2) * D + j];
            float w3 = w2T[(i + 3) * D + j];
#pragma unroll
            for (int ss = 0; ss < 8; ++ss) {
                float4 v = *(const float4*)&s1[sub * 8 + ss][i];
                acc[ss] += v.x * w0 + v.y * w1 + v.z * w2 + v.w * w3;
            }
        }
#pragma unroll
        for (int ss = 0; ss < 8; ++ss) s2[sub * 8 + ss][j] = leaky(acc[ss]);
    }
    __syncthreads();
    if (j < OPS) {
        float bb = b3[j];
#pragma unroll
        for (int ss = 0; ss < 8; ++ss) acc[ss] = bb;
        for (int i = 0; i < D; i += 4) {
            float w0 = w3T[(i + 0) * OPS + j];
            float w1 = w3T[(i + 1) * OPS + j];
            float w2 = w3T[(i + 2) * OPS + j];
            float w3 = w3T[(i + 3) * OPS + j];
#pragma unroll
            for (int ss = 0; ss < 8; ++ss) {
                float4 v = *(const float4*)&s2[sub * 8 + ss][i];
                acc[ss] += v.x * w0 + v.y * w1 + v.z * w2 + v.w * w3;
            }
        }
#pragma unroll
        for (int ss = 0; ss < 8; ++ss) {
            int s = s0 + sub * 8 + ss;
            dout[s * OPS + j] = acc[ss];
        }
    }
}

// ---------------- global pool + stop head ----------------
__global__ void k_pool(const float* __restrict__ out0, const int* __restrict__ batch,
                       float* __restrict__ gsum, float* __restrict__ gcnt) {
    int idx = blockIdx.x * 256 + threadIdx.x;
    if (idx >= NNODES * D) return;
    int n = idx >> 7;
    int j = idx & 127;
    int g = batch[n];
    atomicAdd(&gsum[g * D + j], out0[idx]);
    if (j == 0) atomicAdd(&gcnt[g], 1.0f);
}

__global__ __launch_bounds__(128) void k_gpred(
    const float* __restrict__ gsum, const float* __restrict__ gcnt,
    const float* __restrict__ g1T, const float* __restrict__ b1,
    const float* __restrict__ w2, const float* __restrict__ b2,
    float* __restrict__ dout) {
    __shared__ float mean_s[D];
    __shared__ float red[D];
    int g = blockIdx.x;
    int j = threadIdx.x;
    float denom = fmaxf(gcnt[g], 1.0f);
    mean_s[j] = gsum[g * D + j] / denom;
    __syncthreads();
    float a = b1[j];
    for (int i = 0; i < D; ++i) a += mean_s[i] * g1T[i * D + j];
    a = leaky(a);
    red[j] = a * w2[j];
    __syncthreads();
    for (int off = 64; off > 0; off >>= 1) {
        if (j < off) red[j] += red[j + off];
        __syncthreads();
    }
    if (j == 0) dout[NSTEMS * OPS + g] = red[0] + b2[0];
}

// ---------------- launch ----------------
extern "C" void kernel_launch(void* const* d_in, const int* in_sizes, int n_in,
                              void* d_out, int out_size, void* d_ws, size_t ws_size,
                              hipStream_t stream) {
    const int* x = (const int*)d_in[0];
    const int* stypes = (const int*)d_in[1];
    const int* eattr = (const int*)d_in[2];
    const int* eidx = (const int*)d_in[3];
    const int* sni = (const int*)d_in[4];
    const int* batch = (const int*)d_in[5];
    const float* embBlock = (const float*)d_in[6];
    const float* embStem = (const float*)d_in[7];
    const float* embBond = (const float*)d_in[8];
    const float* b2e_w1 = (const float*)d_in[9];
    const float* b2e_b1 = (const float*)d_in[10];
    const float* b2e_w2 = (const float*)d_in[11];
    const float* b2e_b2 = (const float*)d_in[12];
    const float* conv_root = (const float*)d_in[13];
    const float* conv_bias = (const float*)d_in[14];
    const float* gru_w_ih = (const float*)d_in[15];
    const float* gru_w_hh = (const float*)d_in[16];
    const float* gru_b_ih = (const float*)d_in[17];
    const float* gru_b_hh = (const float*)d_in[18];
    const float* s2p_w1 = (const float*)d_in[19];
    const float* s2p_b1 = (const float*)d_in[20];
    const float* s2p_w2 = (const float*)d_in[21];
    const float* s2p_b2 = (const float*)d_in[22];
    const float* s2p_w3 = (const float*)d_in[23];
    const float* s2p_b3 = (const float*)d_in[24];
    const float* g2p_w1 = (const float*)d_in[25];
    const float* g2p_b1 = (const float*)d_in[26];
    const float* g2p_w2 = (const float*)d_in[27];
    const float* g2p_b2 = (const float*)d_in[28];
    float* out_f = (float*)d_out;

    float* W = (float*)d_ws;
    size_t off = 0;
    auto alloc = [&](size_t words) {
        size_t o = off;
        off += (words + 3) & ~(size_t)3;
        return o;
    };
    float* outA = W + alloc(NNODES * D);
    float* outB = W + alloc(NNODES * D);
    float* hF = W + alloc(NNODES * D);
    float* WihT = W + alloc(128 * 384);
    float* WhhT = W + alloc(128 * 384);
    float* w1T = W + alloc(128 * 128);
    float* w2T = W + alloc(128 * 128);
    float* s1T = W + alloc(256 * 128);
    float* s2T = W + alloc(128 * 128);
    float* s3T = W + alloc(128 * 105);
    float* g1T = W + alloc(128 * 128);
    int* row_start = (int*)(W + alloc(NNODES + 1));
    int* edge_list = (int*)(W + alloc(NEDGES));
    float* inv_deg = W + alloc(NNODES);
    const int zwords = NNODES + NNODES + NGRAPHS * D + NGRAPHS;
    float* zbase = W + alloc(zwords);
    int* deg = (int*)zbase;
    int* fill = deg + NNODES;
    float* gsum = (float*)(fill + NNODES);
    float* gcnt = gsum + NGRAPHS * D;

    k_zero<<<(zwords + 255) / 256, 256, 0, stream>>>(zbase, zwords);
    k_transpose_all<<<dim3(192, 8), 256, 0, stream>>>(
        gru_w_ih, gru_w_hh, b2e_w1, b2e_w2, s2p_w1, s2p_w2, s2p_w3, g2p_w1,
        WihT, WhhT, w1T, w2T, s1T, s2T, s3T, g1T);
    k_deg<<<(NEDGES + 255) / 256, 256, 0, stream>>>(eidx, deg);
    k_scan<<<1, 256, 0, stream>>>(deg, row_start, inv_deg);
    k_scatter<<<(NEDGES + 255) / 256, 256, 0, stream>>>(eidx, row_start, fill, edge_list);
    k_init<<<NNODES / 16, 256, 0, stream>>>(x, embBlock, w1T, b2e_b1, w2T, b2e_b2, outA, hF);

    for (int step = 0; step < NSTEPS; ++step) {
        const float* cur = (step & 1) ? outB : outA;
        float* nxt = (step & 1) ? outA : outB;
        k_nodestep<<<NNODES / 16, 256, 0, stream>>>(
            cur, nxt, hF, embBond, conv_root, conv_bias, WihT, WhhT,
            gru_b_ih, gru_b_hh, eidx, eattr, row_start, edge_list, inv_deg);
    }
    // after 12 steps, final out is in outA
    k_stem<<<NSTEMS / 16, 256, 0, stream>>>(outA, sni, stypes, embStem,
                                            s1T, s2p_b1, s2T, s2p_b2, s3T, s2p_b3, out_f);
    k_pool<<<(NNODES * D + 255) / 256, 256, 0, stream>>>(outA, batch, gsum, gcnt);
    k_gpred<<<NGRAPHS, 128, 0, stream>>>(gsum, gcnt, g1T, g2p_b1, g2p_w2, g2p_b2, out_f);
}

// Round 2
// 515.198 us; speedup vs baseline: 1.9579x; 1.9579x over previous
//
#include <hip/hip_runtime.h>
#include <math.h>

#define D 128
#define NNODES 8192
#define NEDGES 16384
#define NSTEMS 4096
#define NGRAPHS 256
#define NSTEPS 12
#define OPS 105
#define SLOPE 0.01f
#define SLOC_CAP 512
#define MT 32          // nodes per nodestep block
#define LDA 136        // padded halfs per LDS row (272 B, 16B-aligned)

typedef _Float16 half_t;
typedef __attribute__((ext_vector_type(8))) _Float16 f16x8;
typedef __attribute__((ext_vector_type(4))) float f32x4;

__device__ __forceinline__ float leaky(float x) { return x > 0.f ? x : SLOPE * x; }
__device__ __forceinline__ float sigmoidf(float x) { return 1.f / (1.f + expf(-x)); }

// ---------------- setup kernels ----------------

__global__ void k_zero(float* p, int n) {
    int i = blockIdx.x * 256 + threadIdx.x;
    if (i < n) p[i] = 0.f;
}

__global__ void k_deg(const int* __restrict__ eidx, int* __restrict__ deg) {
    int e = blockIdx.x * 256 + threadIdx.x;
    if (e < NEDGES) atomicAdd(&deg[eidx[NEDGES + e]], 1);
}

__global__ void k_scan(const int* __restrict__ deg, int* __restrict__ row_start,
                       float* __restrict__ inv_deg) {
    __shared__ int sums[256];
    int t = threadIdx.x;
    int base = t * 32;
    int s = 0;
    for (int k = 0; k < 32; ++k) s += deg[base + k];
    sums[t] = s;
    __syncthreads();
    for (int off = 1; off < 256; off <<= 1) {
        int v = sums[t];
        int u = (t >= off) ? sums[t - off] : 0;
        __syncthreads();
        sums[t] = v + u;
        __syncthreads();
    }
    int run = sums[t] - s;
    for (int k = 0; k < 32; ++k) {
        int d = deg[base + k];
        row_start[base + k] = run;
        run += d;
        inv_deg[base + k] = (d > 0) ? (1.0f / (float)d) : 0.0f;
    }
    if (t == 255) row_start[NNODES] = run;
}

__global__ void k_scatter(const int* __restrict__ eidx, const int* __restrict__ row_start,
                          int* __restrict__ fill, int* __restrict__ edge_list) {
    int e = blockIdx.x * 256 + threadIdx.x;
    if (e < NEDGES) {
        int d = eidx[NEDGES + e];
        int pos = row_start[d] + atomicAdd(&fill[d], 1);
        edge_list[pos] = e;
    }
}

__device__ __forceinline__ void tr(const float* __restrict__ src, float* __restrict__ dst,
                                   int rows, int cols, int idx) {
    if (idx < rows * cols) {
        int r = idx / cols;
        int c = idx - r * cols;
        dst[c * rows + r] = src[idx];
    }
}

__global__ void k_transpose_all(
    const float* bw1, const float* bw2,
    const float* sw1, const float* sw2, const float* sw3, const float* gw1,
    float* w1T, float* w2T, float* s1T, float* s2T, float* s3T, float* g1T) {
    int idx = blockIdx.x * 256 + threadIdx.x;
    switch (blockIdx.y) {
        case 0: tr(bw1, w1T, 128, 128, idx); break;
        case 1: tr(bw2, w2T, 128, 128, idx); break;
        case 2: tr(sw1, s1T, 128, 256, idx); break;
        case 3: tr(sw2, s2T, 128, 128, idx); break;
        case 4: tr(sw3, s3T, 105, 128, idx); break;
        case 5: tr(gw1, g1T, 128, 128, idx); break;
    }
}

// Pack weights into MFMA B-fragment order, fp16.
// B-frag for 16x16x32: lane L supplies B[k = kt*32 + (L>>4)*8 + j][n = nt*16 + (L&15)], j=0..7.
// dst[((nt*4+kt)*64 + L)*8 + j]
__global__ void k_pack(const float* __restrict__ root, const float* __restrict__ wih,
                       const float* __restrict__ whh,
                       half_t* __restrict__ rootP, half_t* __restrict__ WihP,
                       half_t* __restrict__ WhhP) {
    int idx = blockIdx.x * 256 + threadIdx.x;
    int which = blockIdx.y;
    int NT = (which == 0) ? 8 : 24;           // n-tiles (N=128 or 384)
    if (idx >= NT * 4 * 512) return;
    int j = idx & 7;
    int L = (idx >> 3) & 63;
    int t = idx >> 9;                          // nt*4 + kt
    int kt = t & 3, nt = t >> 2;
    int k = kt * 32 + (L >> 4) * 8 + j;
    int n = nt * 16 + (L & 15);
    if (which == 0) rootP[idx] = (half_t)root[k * D + n];        // out @ root : B[k][n]=root[k][n]
    else if (which == 1) WihP[idx] = (half_t)wih[n * D + k];     // m @ Wih^T  : B[k][n]=wih[n][k]
    else WhhP[idx] = (half_t)whh[n * D + k];
}

// ---------------- node init: out = act(emb@W1.T+b1)@W2.T+b2 ----------------
__global__ __launch_bounds__(256) void k_init(
    const int* __restrict__ x, const float* __restrict__ embBlock,
    const float* __restrict__ w1T, const float* __restrict__ b1,
    const float* __restrict__ w2T, const float* __restrict__ b2,
    half_t* __restrict__ outH, float* __restrict__ hF) {
    __shared__ float es[16][D];
    __shared__ float ts[16][D];
    int tid = threadIdx.x;
    int j = tid & 127;
    int sub = tid >> 7;
    int n0 = blockIdx.x * 16;

    for (int ss = 0; ss < 8; ++ss) {
        int nn = sub * 8 + ss;
        es[nn][j] = embBlock[x[n0 + nn] * D + j];
    }
    __syncthreads();

    float acc[8];
    float bb = b1[j];
#pragma unroll
    for (int ss = 0; ss < 8; ++ss) acc[ss] = bb;
    for (int i = 0; i < D; i += 4) {
        float w0 = w1T[(i + 0) * D + j];
        float w1 = w1T[(i + 1) * D + j];
        float w2 = w1T[(i + 2) * D + j];
        float w3 = w1T[(i + 3) * D + j];
#pragma unroll
        for (int ss = 0; ss < 8; ++ss) {
            float4 v = *(const float4*)&es[sub * 8 + ss][i];
            acc[ss] += v.x * w0 + v.y * w1 + v.z * w2 + v.w * w3;
        }
    }
#pragma unroll
    for (int ss = 0; ss < 8; ++ss) ts[sub * 8 + ss][j] = leaky(acc[ss]);
    __syncthreads();

    bb = b2[j];
#pragma unroll
    for (int ss = 0; ss < 8; ++ss) acc[ss] = bb;
    for (int i = 0; i < D; i += 4) {
        float w0 = w2T[(i + 0) * D + j];
        float w1 = w2T[(i + 1) * D + j];
        float w2v = w2T[(i + 2) * D + j];
        float w3 = w2T[(i + 3) * D + j];
#pragma unroll
        for (int ss = 0; ss < 8; ++ss) {
            float4 v = *(const float4*)&ts[sub * 8 + ss][i];
            acc[ss] += v.x * w0 + v.y * w1 + v.z * w2v + v.w * w3;
        }
    }
#pragma unroll
    for (int ss = 0; ss < 8; ++ss) {
        int n = n0 + sub * 8 + ss;
        hF[n * D + j] = acc[ss];
        outH[n * D + j] = (half_t)acc[ss];
    }
}

// ---------------- fused conv+GRU step, MFMA fp16 ----------------
// 512 threads = 8 waves; block handles MT=32 nodes (2 m-tiles of 16).
// Wave w owns gate-columns [16w, 16w+16): conv n-tile w; gi/gh n-tiles {g*8+w}.
__global__ __launch_bounds__(512) void k_nodestep(
    const half_t* __restrict__ outCur, half_t* __restrict__ outNxt, float* __restrict__ hF,
    const float* __restrict__ bond,
    const half_t* __restrict__ rootP, const half_t* __restrict__ WihP,
    const half_t* __restrict__ WhhP,
    const float* __restrict__ cbias, const float* __restrict__ bih,
    const float* __restrict__ bhh,
    const int* __restrict__ eidx, const int* __restrict__ eattr,
    const int* __restrict__ row_start, const int* __restrict__ edge_list,
    const float* __restrict__ inv_deg) {
    __shared__ __align__(16) half_t As_out[MT * LDA];
    __shared__ __align__(16) half_t As_h[MT * LDA];
    __shared__ __align__(16) half_t As_m[MT * LDA];
    __shared__ float sloc[SLOC_CAP];

    const int tid = threadIdx.x;
    const int w = tid >> 6;
    const int lane = tid & 63;
    const int quad = lane >> 4;
    const int l16 = lane & 15;
    const int n0 = blockIdx.x * MT;

    // --- stage out (fp16) and h (fp32->fp16) tiles into LDS ---
    {
        int row = tid >> 4;              // 32 rows
        int col = (tid & 15) * 8;        // 8 halfs each
        f16x8 v = *(const f16x8*)(outCur + (size_t)(n0 + row) * D + col);
        *(f16x8*)&As_out[row * LDA + col] = v;
        const float4* hsrc = (const float4*)(hF + (size_t)(n0 + row) * D + col);
        float4 h0 = hsrc[0], h1 = hsrc[1];
        f16x8 hv;
        hv[0] = (half_t)h0.x; hv[1] = (half_t)h0.y; hv[2] = (half_t)h0.z; hv[3] = (half_t)h0.w;
        hv[4] = (half_t)h1.x; hv[5] = (half_t)h1.y; hv[6] = (half_t)h1.z; hv[7] = (half_t)h1.w;
        *(f16x8*)&As_h[row * LDA + col] = hv;
    }
    const int p0 = row_start[n0];
    const int p1 = row_start[n0 + MT];

    // --- edge dots: s_e = dot(out[src], bond[ea0]) ---
    for (int p = p0 + w; p < p1; p += 8) {
        int e = edge_list[p];
        int s = eidx[e];
        int a0 = eattr[2 * e];
        float v = (float)outCur[(size_t)s * D + lane] * bond[a0 * D + lane] +
                  (float)outCur[(size_t)s * D + 64 + lane] * bond[a0 * D + 64 + lane];
#pragma unroll
        for (int off = 32; off >= 1; off >>= 1) v += __shfl_xor(v, off, 64);
        int rel = p - p0;
        if (lane == 0 && rel < SLOC_CAP) sloc[rel] = v;
    }
    __syncthreads();

    // --- conv GEMM: C = out_tile @ root, wave's 16 cols ---
    f32x4 convAcc[2] = {f32x4{0.f, 0.f, 0.f, 0.f}, f32x4{0.f, 0.f, 0.f, 0.f}};
#pragma unroll
    for (int kt = 0; kt < 4; ++kt) {
        f16x8 b = *(const f16x8*)(rootP + (size_t)((w * 4 + kt) * 64 + lane) * 8);
        f16x8 a0 = *(const f16x8*)&As_out[(0 * 16 + l16) * LDA + kt * 32 + quad * 8];
        f16x8 a1 = *(const f16x8*)&As_out[(1 * 16 + l16) * LDA + kt * 32 + quad * 8];
        convAcc[0] = __builtin_amdgcn_mfma_f32_16x16x32_f16(a0, b, convAcc[0], 0, 0, 0);
        convAcc[1] = __builtin_amdgcn_mfma_f32_16x16x32_f16(a1, b, convAcc[1], 0, 0, 0);
    }

    // --- gh GEMM: h_tile @ Whh^T, wave's 16 cols x 3 gates ---
    f32x4 ghAcc[2][3];
#pragma unroll
    for (int mt = 0; mt < 2; ++mt)
#pragma unroll
        for (int g = 0; g < 3; ++g) ghAcc[mt][g] = f32x4{0.f, 0.f, 0.f, 0.f};
#pragma unroll
    for (int kt = 0; kt < 4; ++kt) {
        f16x8 a0 = *(const f16x8*)&As_h[(0 * 16 + l16) * LDA + kt * 32 + quad * 8];
        f16x8 a1 = *(const f16x8*)&As_h[(1 * 16 + l16) * LDA + kt * 32 + quad * 8];
#pragma unroll
        for (int g = 0; g < 3; ++g) {
            f16x8 b = *(const f16x8*)(WhhP + (size_t)(((g * 8 + w) * 4 + kt) * 64 + lane) * 8);
            ghAcc[0][g] = __builtin_amdgcn_mfma_f32_16x16x32_f16(a0, b, ghAcc[0][g], 0, 0, 0);
            ghAcc[1][g] = __builtin_amdgcn_mfma_f32_16x16x32_f16(a1, b, ghAcc[1][g], 0, 0, 0);
        }
    }

    // --- edge aggregation at C-fragment positions, m = leaky(conv + bias + agg/deg) ---
    const int c = w * 16 + l16;          // this lane's column, 0..127
    {
        float cb = cbias[c];
#pragma unroll
        for (int mt = 0; mt < 2; ++mt) {
#pragma unroll
            for (int r = 0; r < 4; ++r) {
                int rowl = mt * 16 + quad * 4 + r;
                int node = n0 + rowl;
                float a = 0.f;
                int q0 = row_start[node], q1 = row_start[node + 1];
                for (int p = q0; p < q1; ++p) {
                    int e = edge_list[p];
                    int a1i = eattr[2 * e + 1];
                    int rel = p - p0;
                    float sv;
                    if (rel < SLOC_CAP) sv = sloc[rel];
                    else {
                        int s2 = eidx[e];
                        int a0i = eattr[2 * e];
                        sv = 0.f;
                        for (int i = 0; i < D; ++i)
                            sv += (float)outCur[(size_t)s2 * D + i] * bond[a0i * D + i];
                    }
                    a += sv * bond[a1i * D + c];
                }
                float m = convAcc[mt][r] + cb + a * inv_deg[node];
                As_m[rowl * LDA + c] = (half_t)leaky(m);
            }
        }
    }
    __syncthreads();

    // --- gi GEMM: m_tile @ Wih^T ---
    f32x4 giAcc[2][3];
#pragma unroll
    for (int mt = 0; mt < 2; ++mt)
#pragma unroll
        for (int g = 0; g < 3; ++g) giAcc[mt][g] = f32x4{0.f, 0.f, 0.f, 0.f};
#pragma unroll
    for (int kt = 0; kt < 4; ++kt) {
        f16x8 a0 = *(const f16x8*)&As_m[(0 * 16 + l16) * LDA + kt * 32 + quad * 8];
        f16x8 a1 = *(const f16x8*)&As_m[(1 * 16 + l16) * LDA + kt * 32 + quad * 8];
#pragma unroll
        for (int g = 0; g < 3; ++g) {
            f16x8 b = *(const f16x8*)(WihP + (size_t)(((g * 8 + w) * 4 + kt) * 64 + lane) * 8);
            giAcc[0][g] = __builtin_amdgcn_mfma_f32_16x16x32_f16(a0, b, giAcc[0][g], 0, 0, 0);
            giAcc[1][g] = __builtin_amdgcn_mfma_f32_16x16x32_f16(a1, b, giAcc[1][g], 0, 0, 0);
        }
    }

    // --- GRU combine (elementwise on fragments) ---
    {
        float bi0 = bih[c], bi1 = bih[D + c], bi2 = bih[2 * D + c];
        float bh0 = bhh[c], bh1 = bhh[D + c], bh2 = bhh[2 * D + c];
#pragma unroll
        for (int mt = 0; mt < 2; ++mt) {
#pragma unroll
            for (int r = 0; r < 4; ++r) {
                int node = n0 + mt * 16 + quad * 4 + r;
                float rg = sigmoidf(giAcc[mt][0][r] + bi0 + ghAcc[mt][0][r] + bh0);
                float z = sigmoidf(giAcc[mt][1][r] + bi1 + ghAcc[mt][1][r] + bh1);
                float nn = tanhf(giAcc[mt][2][r] + bi2 + rg * (ghAcc[mt][2][r] + bh2));
                float hv = hF[(size_t)node * D + c];
                float hnew = (1.f - z) * nn + z * hv;
                hF[(size_t)node * D + c] = hnew;
                outNxt[(size_t)node * D + c] = (half_t)hnew;
            }
        }
    }
}

// ---------------- stem head (fp32) ----------------
__global__ __launch_bounds__(256) void k_stem(
    const float* __restrict__ out0, const int* __restrict__ sni, const int* __restrict__ stypes,
    const float* __restrict__ embStem,
    const float* __restrict__ w1T, const float* __restrict__ b1,
    const float* __restrict__ w2T, const float* __restrict__ b2,
    const float* __restrict__ w3T, const float* __restrict__ b3,
    float* __restrict__ dout) {
    __shared__ float cat[16][2 * D];
    __shared__ float s1[16][D];
    __shared__ float s2[16][D];
    int tid = threadIdx.x;
    int j = tid & 127;
    int sub = tid >> 7;
    int s0 = blockIdx.x * 16;

    for (int ss = 0; ss < 16; ++ss) {
        int s = s0 + ss;
        if (tid < 128) cat[ss][tid] = out0[sni[s] * D + tid];
        else cat[ss][tid] = embStem[stypes[s] * D + (tid - 128)];
    }
    __syncthreads();

    float acc[8];
    {
        float bb = b1[j];
#pragma unroll
        for (int ss = 0; ss < 8; ++ss) acc[ss] = bb;
        for (int i = 0; i < 2 * D; i += 4) {
            float w0 = w1T[(i + 0) * D + j];
            float w1 = w1T[(i + 1) * D + j];
            float w2 = w1T[(i + 2) * D + j];
            float w3 = w1T[(i + 3) * D + j];
#pragma unroll
            for (int ss = 0; ss < 8; ++ss) {
                float4 v = *(const float4*)&cat[sub * 8 + ss][i];
                acc[ss] += v.x * w0 + v.y * w1 + v.z * w2 + v.w * w3;
            }
        }
#pragma unroll
        for (int ss = 0; ss < 8; ++ss) s1[sub * 8 + ss][j] = leaky(acc[ss]);
    }
    __syncthreads();
    {
        float bb = b2[j];
#pragma unroll
        for (int ss = 0; ss < 8; ++ss) acc[ss] = bb;
        for (int i = 0; i < D; i += 4) {
            float w0 = w2T[(i + 0) * D + j];
            float w1 = w2T[(i + 1) * D + j];
            float w2 = w2T[(i + 2) * D + j];
            float w3 = w2T[(i + 3) * D + j];
#pragma unroll
            for (int ss = 0; ss < 8; ++ss) {
                float4 v = *(const float4*)&s1[sub * 8 + ss][i];
                acc[ss] += v.x * w0 + v.y * w1 + v.z * w2 + v.w * w3;
            }
        }
#pragma unroll
        for (int ss = 0; ss < 8; ++ss) s2[sub * 8 + ss][j] = leaky(acc[ss]);
    }
    __syncthreads();
    if (j < OPS) {
        float bb = b3[j];
#pragma unroll
        for (int ss = 0; ss < 8; ++ss) acc[ss] = bb;
        for (int i = 0; i < D; i += 4) {
            float w0 = w3T[(i + 0) * OPS + j];
            float w1 = w3T[(i + 1) * OPS + j];
            float w2 = w3T[(i + 2) * OPS + j];
            float w3 = w3T[(i + 3) * OPS + j];
#pragma unroll
            for (int ss = 0; ss < 8; ++ss) {
                float4 v = *(const float4*)&s2[sub * 8 + ss][i];
                acc[ss] += v.x * w0 + v.y * w1 + v.z * w2 + v.w * w3;
            }
        }
#pragma unroll
        for (int ss = 0; ss < 8; ++ss) {
            int s = s0 + sub * 8 + ss;
            dout[s * OPS + j] = acc[ss];
        }
    }
}

// ---------------- global pool + stop head ----------------
__global__ void k_pool(const float* __restrict__ out0, const int* __restrict__ batch,
                       float* __restrict__ gsum, float* __restrict__ gcnt) {
    int idx = blockIdx.x * 256 + threadIdx.x;
    if (idx >= NNODES * D) return;
    int n = idx >> 7;
    int j = idx & 127;
    int g = batch[n];
    atomicAdd(&gsum[g * D + j], out0[idx]);
    if (j == 0) atomicAdd(&gcnt[g], 1.0f);
}

__global__ __launch_bounds__(128) void k_gpred(
    const float* __restrict__ gsum, const float* __restrict__ gcnt,
    const float* __restrict__ g1T, const float* __restrict__ b1,
    const float* __restrict__ w2, const float* __restrict__ b2,
    float* __restrict__ dout) {
    __shared__ float mean_s[D];
    __shared__ float red[D];
    int g = blockIdx.x;
    int j = threadIdx.x;
    float denom = fmaxf(gcnt[g], 1.0f);
    mean_s[j] = gsum[g * D + j] / denom;
    __syncthreads();
    float a = b1[j];
    for (int i = 0; i < D; ++i) a += mean_s[i] * g1T[i * D + j];
    a = leaky(a);
    red[j] = a * w2[j];
    __syncthreads();
    for (int off = 64; off > 0; off >>= 1) {
        if (j < off) red[j] += red[j + off];
        __syncthreads();
    }
    if (j == 0) dout[NSTEMS * OPS + g] = red[0] + b2[0];
}

// ---------------- launch ----------------
extern "C" void kernel_launch(void* const* d_in, const int* in_sizes, int n_in,
                              void* d_out, int out_size, void* d_ws, size_t ws_size,
                              hipStream_t stream) {
    const int* x = (const int*)d_in[0];
    const int* stypes = (const int*)d_in[1];
    const int* eattr = (const int*)d_in[2];
    const int* eidx = (const int*)d_in[3];
    const int* sni = (const int*)d_in[4];
    const int* batch = (const int*)d_in[5];
    const float* embBlock = (const float*)d_in[6];
    const float* embStem = (const float*)d_in[7];
    const float* embBond = (const float*)d_in[8];
    const float* b2e_w1 = (const float*)d_in[9];
    const float* b2e_b1 = (const float*)d_in[10];
    const float* b2e_w2 = (const float*)d_in[11];
    const float* b2e_b2 = (const float*)d_in[12];
    const float* conv_root = (const float*)d_in[13];
    const float* conv_bias = (const float*)d_in[14];
    const float* gru_w_ih = (const float*)d_in[15];
    const float* gru_w_hh = (const float*)d_in[16];
    const float* gru_b_ih = (const float*)d_in[17];
    const float* gru_b_hh = (const float*)d_in[18];
    const float* s2p_w1 = (const float*)d_in[19];
    const float* s2p_b1 = (const float*)d_in[20];
    const float* s2p_w2 = (const float*)d_in[21];
    const float* s2p_b2 = (const float*)d_in[22];
    const float* s2p_w3 = (const float*)d_in[23];
    const float* s2p_b3 = (const float*)d_in[24];
    const float* g2p_w1 = (const float*)d_in[25];
    const float* g2p_b1 = (const float*)d_in[26];
    const float* g2p_w2 = (const float*)d_in[27];
    const float* g2p_b2 = (const float*)d_in[28];
    float* out_f = (float*)d_out;

    float* W = (float*)d_ws;
    size_t off = 0;
    auto alloc = [&](size_t words) {
        size_t o = off;
        off += (words + 3) & ~(size_t)3;
        return o;
    };
    half_t* outHA = (half_t*)(W + alloc(NNODES * D / 2));
    half_t* outHB = (half_t*)(W + alloc(NNODES * D / 2));
    float* hF = W + alloc(NNODES * D);
    half_t* rootP = (half_t*)(W + alloc(8 * 4 * 512 / 2));
    half_t* WihP = (half_t*)(W + alloc(24 * 4 * 512 / 2));
    half_t* WhhP = (half_t*)(W + alloc(24 * 4 * 512 / 2));
    float* w1T = W + alloc(128 * 128);
    float* w2T = W + alloc(128 * 128);
    float* s1T = W + alloc(256 * 128);
    float* s2T = W + alloc(128 * 128);
    float* s3T = W + alloc(128 * 105);
    float* g1T = W + alloc(128 * 128);
    int* row_start = (int*)(W + alloc(NNODES + 1));
    int* edge_list = (int*)(W + alloc(NEDGES));
    float* inv_deg = W + alloc(NNODES);
    const int zwords = NNODES + NNODES + NGRAPHS * D + NGRAPHS;
    float* zbase = W + alloc(zwords);
    int* deg = (int*)zbase;
    int* fill = deg + NNODES;
    float* gsum = (float*)(fill + NNODES);
    float* gcnt = gsum + NGRAPHS * D;

    k_zero<<<(zwords + 255) / 256, 256, 0, stream>>>(zbase, zwords);
    k_transpose_all<<<dim3(128, 6), 256, 0, stream>>>(
        b2e_w1, b2e_w2, s2p_w1, s2p_w2, s2p_w3, g2p_w1,
        w1T, w2T, s1T, s2T, s3T, g1T);
    k_pack<<<dim3(192, 3), 256, 0, stream>>>(conv_root, gru_w_ih, gru_w_hh,
                                             rootP, WihP, WhhP);
    k_deg<<<(NEDGES + 255) / 256, 256, 0, stream>>>(eidx, deg);
    k_scan<<<1, 256, 0, stream>>>(deg, row_start, inv_deg);
    k_scatter<<<(NEDGES + 255) / 256, 256, 0, stream>>>(eidx, row_start, fill, edge_list);
    k_init<<<NNODES / 16, 256, 0, stream>>>(x, embBlock, w1T, b2e_b1, w2T, b2e_b2, outHA, hF);

    for (int step = 0; step < NSTEPS; ++step) {
        const half_t* cur = (step & 1) ? outHB : outHA;
        half_t* nxt = (step & 1) ? outHA : outHB;
        k_nodestep<<<NNODES / MT, 512, 0, stream>>>(
            cur, nxt, hF, embBond, rootP, WihP, WhhP,
            conv_bias, gru_b_ih, gru_b_hh,
            eidx, eattr, row_start, edge_list, inv_deg);
    }
    // final hidden state (== out) lives in hF (fp32)
    k_stem<<<NSTEMS / 16, 256, 0, stream>>>(hF, sni, stypes, embStem,
                                            s1T, s2p_b1, s2T, s2p_b2, s3T, s2p_b3, out_f);
    k_pool<<<(NNODES * D + 255) / 256, 256, 0, stream>>>(hF, batch, gsum, gcnt);
    k_gpred<<<NGRAPHS, 128, 0, stream>>>(gsum, gcnt, g1T, g2p_b1, g2p_w2, g2p_b2, out_f);
}